// Round 11
// baseline (1529.565 us; speedup 1.0000x reference)
//
#include <hip/hip_runtime.h>
#include <math.h>

#define N_NODE 200
#define RING   512
#define ROWF   545          // 512 + 32 mirror + 1 (odd stride -> conflict-free ring writes)
#define NSTEP  500
#define TB     32
#define NB     16           // ceil(500/32); last block kmax=20
#define NWG    8
#define NTHR   512          // 2 teams x 256
#define JSL    25           // j-rows per WG slice
#define TJ0    13           // team-0 rows (team 1: 12)
#define NEARCAP 32          // near band d < 32
#define MDEP   36           // Mrec depth, mod-36 slots
#define MSZ    (MDEP * N_NODE)   // 7200

// ---- ws layout (float element offsets) ----
#define FPBUF   (2 * NWG * N_NODE * TB)   // 102400 floats per parity (16 virtual WGs)
#define OFF_FP  0                          // [2][16][200][32] far partials
#define OFF_BAR (2 * FPBUF)                // [64] int barrier counters
#define WS_NEED ((size_t)(2 * FPBUF + 64) * 4)

// ---- static LDS layout (byte offsets into smem[]) ----
#define SM_RED   0        // double[8]                      -> 64
#define SM_MREC  64       // float[36*200] = 28800          -> 28864
#define SM_UN    28864    // float2[32][200] = 51200        -> 80064  (build: near tables)
#define SM_LEDS  80064    // float[32][200] = 25600         -> 105664
#define SM_RING  105664   // float[25][545] = 54500         -> 160164
#define SM_TOTAL 160164
// build-phase aliases (inside SM_UN)
#define SM_NOFF  SM_UN                  // u32 [32][200] = 25600
#define SM_NW    (SM_UN + 25600)        // f32 [32][200] = 25600
// epilogue overlays (post-loop; below SM_RING until hEb flushed)
#define SM_LMT   64       // float[64*200] -> 51264
#define SM_DIFF  51264    // float[200*50] -> 91264

// ---- fast transcendentals (v_exp_f32-based, ~1e-6 rel err) ----
__device__ __forceinline__ float ftanh(float x) {
    float ax = fabsf(x);
    float t  = __expf(-2.0f * ax);
    float r  = __fdividef(1.0f - t, 1.0f + t);
    return copysignf(r, x);
}
__device__ __forceinline__ float sigm(float x) {
    return __fdividef(5.0f, 1.0f + __expf(0.56f * (6.0f - x)));
}
__device__ __forceinline__ float satf(float x) {
    return 1000.0f * ftanh(x * 0.001f);
}

__device__ __forceinline__ void grid_barrier(int* slot, int nwg) {
    __syncthreads();
    if (threadIdx.x == 0) {
        __threadfence();
        __hip_atomic_fetch_add(slot, 1, __ATOMIC_ACQ_REL, __HIP_MEMORY_SCOPE_AGENT);
        while (__hip_atomic_load(slot, __ATOMIC_ACQUIRE, __HIP_MEMORY_SCOPE_AGENT) < nwg) {
            __builtin_amdgcn_s_sleep(2);
        }
        __threadfence();
    }
    __syncthreads();
}

__global__ void zero_bar(int* bar) {
    if (threadIdx.x < 64) bar[threadIdx.x] = 0;
}

__global__ __launch_bounds__(NTHR, 2)
void jansen_tlp(const float* __restrict__ inp, const float* __restrict__ noise_in,
                const float* __restrict__ hx,  const float* __restrict__ hE,
                const float* __restrict__ sc,  const float* __restrict__ wbb,
                const float* __restrict__ lm,  const int*   __restrict__ delays,
                float* __restrict__ out, float* __restrict__ ws)
{
    __shared__ char smem[SM_TOTAL];
    double*   red  = (double*)(smem + SM_RED);
    float*    Mrec = (float*)(smem + SM_MREC);
    unsigned* nOFF = (unsigned*)(smem + SM_NOFF);   // build-phase alias
    float*    nW   = (float*)(smem + SM_NW);        // build-phase alias
    float2*   unS  = (float2*)(smem + SM_UN);       // main-loop alias
    float*    LEdS = (float*)(smem + SM_LEDS);
    float*    ringS= (float*)(smem + SM_RING);

    const int tid   = threadIdx.x;
    const int wg    = blockIdx.x;
    const int team  = tid >> 8;          // 0 or 1 (wave-uniform)
    const int i     = tid & 255;         // node id (active if < 200)
    const int jlo_w = wg * JSL;          // WG's 25-row base
    const int jlo_t = jlo_w + team * TJ0;
    const int jcnt  = team ? (JSL - TJ0) : TJ0;   // 12 : 13

    float* fp  = ws + OFF_FP;
    int*   bar = (int*)(ws + OFF_BAR);

    // ---- pass A: Frobenius norm of wl (redundant per WG; exact libm) ----
    double ssq = 0.0;
    for (int q = tid; q < N_NODE * N_NODE; q += NTHR) {
        int j = q / N_NODE, ii = q - j * N_NODE;
        float w1 = expf(wbb[ii * N_NODE + j]) * sc[ii * N_NODE + j];
        float w2 = expf(wbb[j * N_NODE + ii]) * sc[j * N_NODE + ii];
        float wl = log1pf(0.5f * (w1 + w2));
        ssq += (double)wl * (double)wl;
    }
    #pragma unroll
    for (int off = 32; off > 0; off >>= 1) ssq += __shfl_down(ssq, off, 64);
    if ((tid & 63) == 0) red[tid >> 6] = ssq;

    // ---- ring init: pos x holds M[-1-dd], dd=511-x; mirror [512..543] copies [0..31] ----
    for (int p = tid; p < JSL * ROWF; p += NTHR) {
        int jl = p / ROWF, x = p - jl * ROWF;
        float v = 0.0f;
        if (x < 544) {
            int dd = (x < RING) ? (511 - x) : (1023 - x);
            if (dd < 500) v = hE[(jlo_w + jl) * 500 + dd];
        }
        ringS[p] = v;
    }
    // ---- Mrec init: M[-q] at slot (36-q), q=1..32 -> slot s in [4,35]: hE[j][35-s] ----
    for (int p = tid; p < MSZ; p += NTHR) {
        int s = p / N_NODE, j = p - s * N_NODE;
        Mrec[p] = (s >= 4) ? hE[j * 500 + (35 - s)] : 0.0f;
    }
    // ---- zero-init near tables (padding entries: offset 0, weight 0) ----
    for (int p = tid; p < NEARCAP * N_NODE; p += NTHR) {
        nOFF[p] = 0u;
        nW[p]   = 0.0f;
    }
    __syncthreads();
    if (tid == 0) {
        double s = 0.0;
        #pragma unroll
        for (int r = 0; r < 8; ++r) s += red[r];
        red[0] = 1.0 / sqrt(s);
    }
    __syncthreads();
    const float inv = (float)red[0];

    // ---- pass B: near lists (both teams, identical duplicate writes), own far rows, state ----
    float rowsum = 0.0f;
    float M = 0, E = 0, I = 0, Mvv = 0, Evv = 0, Ivv = 0;
    float wreg[TJ0];
    int   ereg[TJ0];
    #pragma unroll
    for (int jl = 0; jl < TJ0; ++jl) { wreg[jl] = 0.0f; ereg[jl] = 511; }
    int cnt = 0;
    if (i < N_NODE) {
        for (int j = 0; j < N_NODE; ++j) {
            float w1 = expf(wbb[i * N_NODE + j]) * sc[i * N_NODE + j];
            float w2 = expf(wbb[j * N_NODE + i]) * sc[j * N_NODE + i];
            float w  = log1pf(0.5f * (w1 + w2)) * inv;
            int d = delays[j * N_NODE + i];
            rowsum += w;
            if (d < NEARCAP && cnt < NEARCAP) {
                nOFF[cnt * N_NODE + i] = (unsigned)((35 - d) * N_NODE + j);
                nW  [cnt * N_NODE + i] = w;
                ++cnt;
            }
        }
        #pragma unroll
        for (int jl = 0; jl < TJ0; ++jl) {
            if (jl < jcnt) {
                int j = jlo_t + jl;
                float w1 = expf(wbb[i * N_NODE + j]) * sc[i * N_NODE + j];
                float w2 = expf(wbb[j * N_NODE + i]) * sc[j * N_NODE + i];
                float w  = log1pf(0.5f * (w1 + w2)) * inv;
                int d = delays[j * N_NODE + i];
                wreg[jl] = (d < NEARCAP) ? 0.0f : w;
                ereg[jl] = 511 - d;
            }
        }
        M   = hx[i * 6 + 0]; E   = hx[i * 6 + 1]; I   = hx[i * 6 + 2];
        Mvv = hx[i * 6 + 3]; Evv = hx[i * 6 + 4]; Ivv = hx[i * 6 + 5];
    }

    // ---- near list -> REGISTERS (loop-invariant; static indices only) ----
    int   noffR[NEARCAP];
    float nwR[NEARCAP];
    {
        const int ii = (i < N_NODE) ? i : 0;
        #pragma unroll
        for (int n = 0; n < NEARCAP; ++n) {
            noffR[n] = (int)nOFF[n * N_NODE + ii];
            nwR[n]   = nW[n * N_NODE + ii];
        }
    }
    __syncthreads();   // build tables dead; unS alias takes over

    // ---------------- main loop over 32-step blocks (serial phases) ----------------
    for (int b = 0; b < NB; ++b) {
        const int t0 = b * TB;
        float* fpb = fp + (b & 1) * FPBUF;

        // ---- far phase: own team rows, contiguous mirror-padded reads ----
        if (i < N_NODE) {
            float ac[TB];
            #pragma unroll
            for (int k = 0; k < TB; ++k) ac[k] = 0.0f;
            #pragma unroll
            for (int jl = 0; jl < TJ0; ++jl) {
                float w  = wreg[jl];
                int   p0 = (t0 + ereg[jl]) & 511;
                int   lr = team * TJ0 + jl; if (lr > 24) lr = 24;   // pad clamp (w=0)
                const float* rb = ringS + lr * ROWF + p0;
                #pragma unroll
                for (int k = 0; k < TB; ++k)
                    ac[k] = fmaf(w, rb[k], ac[k]);
            }
            float4* fpw = (float4*)(fpb + ((wg * 2 + team) * N_NODE + i) * TB);
            #pragma unroll
            for (int q = 0; q < 8; ++q)
                fpw[q] = make_float4(ac[4*q+0], ac[4*q+1], ac[4*q+2], ac[4*q+3]);

            // ---- stage this block's u/noise (16 steps per team); drain absorbed by barrier ----
            #pragma unroll
            for (int k2 = 0; k2 < 16; ++k2) {
                int k = team * 16 + k2;
                int t = t0 + k;
                float uv = 0.0f, nv = 0.0f;
                if (t < NSTEP) {
                    int bb = t / 10, h = t - 10 * bb;
                    uv = inp     [i * 500 + h * 50 + bb];
                    nv = noise_in[i * 500 + h * 50 + bb];
                }
                unS[k * N_NODE + i] = make_float2(uv, nv);
            }
        }

        grid_barrier(bar + b, NWG);

        // ---- gather partials: team t handles c-quadrants t*4..t*4+3 over 16 rows ----
        if (i < N_NODE) {
            const float* basep = fpb + i * TB;
            #pragma unroll
            for (int c2 = 0; c2 < 4; ++c2) {
                int c = (team << 2) + c2;
                float sx = 0, sy = 0, sz = 0, sw = 0;
                #pragma unroll
                for (int g = 0; g < 2 * NWG; ++g) {
                    float4 q = *(const float4*)(basep + g * (N_NODE * TB) + c * 4);
                    sx += q.x; sy += q.y; sz += q.z; sw += q.w;
                }
                LEdS[(c * 4 + 0) * N_NODE + i] = sx;
                LEdS[(c * 4 + 1) * N_NODE + i] = sy;
                LEdS[(c * 4 + 2) * N_NODE + i] = sz;
                LEdS[(c * 4 + 3) * N_NODE + i] = sw;
            }
        }
        __syncthreads();

        // ---- inner per-step phase: BOTH teams run identical sim (TLP) ----
        const int kmax = (NSTEP - t0 < TB) ? (NSTEP - t0) : TB;
        int s36 = t0 % MDEP;
        int bcur = t0 / 10, hcur = t0 - 10 * bcur;
        const bool ringw = (i >= jlo_t) && (i < jlo_t + jcnt);
        const int  rbase = (i - jlo_w) * ROWF;
        for (int k = 0; k < kmax; ++k) {
            const int t = t0 + k;
            if (i < N_NODE) {
                const int base36 = s36 * N_NODE;
                float a0 = LEdS[k * N_NODE + i];
                float a1 = 0.0f, a2 = 0.0f, a3 = 0.0f;
                #pragma unroll
                for (int n = 0; n < 8; ++n) {
                    int a = base36 + noffR[n]; if (a >= MSZ) a -= MSZ;
                    a0 = fmaf(nwR[n], Mrec[a], a0);
                }
                if (cnt > 8) {
                    #pragma unroll
                    for (int n = 8; n < 16; ++n) {
                        int a = base36 + noffR[n]; if (a >= MSZ) a -= MSZ;
                        a1 = fmaf(nwR[n], Mrec[a], a1);
                    }
                }
                if (cnt > 16) {
                    #pragma unroll
                    for (int n = 16; n < 24; ++n) {
                        int a = base36 + noffR[n]; if (a >= MSZ) a -= MSZ;
                        a2 = fmaf(nwR[n], Mrec[a], a2);
                    }
                }
                if (cnt > 24) {
                    #pragma unroll
                    for (int n = 24; n < 32; ++n) {
                        int a = base36 + noffR[n]; if (a >= MSZ) a -= MSZ;
                        a3 = fmaf(nwR[n], Mrec[a], a3);
                    }
                }
                float LEd = (a0 + a1) + (a2 + a3);
                float2 un = unS[k * N_NODE + i];
                float u  = un.x;
                float nz = un.y;
                float rM = sigm(E - I);
                float rE = 250.0f * nz + 1000.01f * (LEd - rowsum * E) + 108.01f * sigm(135.01f * M);
                float rI = 33.76f * sigm(33.76f * M);
                float ddM = M + 1e-4f * Mvv;
                float ddE = E + 1e-4f * Evv;
                float ddI = I + 1e-4f * Ivv;
                float uu  = u + 500.0f * ftanh(rM * 0.002f);
                float ddMv = Mvv + 1e-4f * (328.25f * uu - 202.0f * Mvv - 10201.0f * M);
                float uE  = 500.0f * ftanh(rE * 0.002f);
                float ddEv = Evv + 1e-4f * (328.25f * uE - 202.0f * Evv - 10201.0f * E);
                float uI  = 500.0f * ftanh(rI * 0.002f);
                float ddIv = Ivv + 1e-4f * (1122.0f * uI - 102.0f * Ivv - 2601.0f * I);
                M   = satf(ddM);  E   = satf(ddE);  I   = satf(ddI);
                Mvv = satf(ddMv); Evv = satf(ddEv); Ivv = satf(ddIv);
                if (team == 0) Mrec[base36 + i] = M;
                if (ringw) {
                    int pt = t & 511;
                    ringS[rbase + pt] = M;
                    if (pt < 32) ringS[rbase + pt + 512] = M;
                }
                if (team == 0 && wg == 0 && hcur == 9) {
                    out[ 4400 + i * 50 + bcur] = E;
                    out[14400 + i * 50 + bcur] = I;
                    out[24400 + i * 50 + bcur] = M;
                    out[34400 + i * 50 + bcur] = Evv;
                    out[44400 + i * 50 + bcur] = Ivv;
                    out[54400 + i * 50 + bcur] = Mvv;
                }
                ++hcur; if (hcur == 10) { hcur = 0; ++bcur; }
                ++s36; if (s36 == MDEP) s36 = 0;
            }
            __syncthreads();
        }
    }

    // ---------------- epilogue ----------------
    // hEb slice: rows [jlo_w, jlo_w+25) from LDS ring
    for (int p = tid; p < JSL * 500; p += NTHR) {
        int jl = p / 500, dd = p - jl * 500;
        out[64400 + (jlo_w + jl) * 500 + dd] = ringS[jl * ROWF + ((499 - dd) & 511)];
    }
    if (wg != 0) return;

    if (team == 0 && i < N_NODE) {
        out[3200 + i * 6 + 0] = M;
        out[3200 + i * 6 + 1] = E;
        out[3200 + i * 6 + 2] = I;
        out[3200 + i * 6 + 3] = Mvv;
        out[3200 + i * 6 + 4] = Evv;
        out[3200 + i * 6 + 5] = Ivv;
    }

    float* lmt  = (float*)(smem + SM_LMT);
    float* diff = (float*)(smem + SM_DIFF);
    __syncthreads();
    if (tid < 64) {
        float s = 0.0f;
        for (int n = 0; n < N_NODE; ++n) { float v = lm[tid * N_NODE + n]; s += v * v; }
        float ivn = 1.0f / sqrtf(s);
        for (int n = 0; n < N_NODE; ++n) lmt[tid * N_NODE + n] = lm[tid * N_NODE + n] * ivn;
    }
    __syncthreads();
    if (tid < N_NODE) {
        float s = 0.0f;
        for (int o = 0; o < 64; ++o) s += lmt[o * N_NODE + tid];
        s *= (1.0f / 64.0f);
        for (int o = 0; o < 64; ++o) lmt[o * N_NODE + tid] -= s;
    }
    __syncthreads();
    for (int p = tid; p < 10000; p += NTHR) diff[p] = out[4400 + p] - out[14400 + p];
    __syncthreads();
    for (int p = tid; p < 3200; p += NTHR) {
        int o = p / 50, bb = p - o * 50;
        float s = 0.0f;
        for (int n = 0; n < N_NODE; ++n)
            s = fmaf(lmt[o * N_NODE + n], diff[n * 50 + bb], s);
        out[p] = 5.0f * s - 2.0f;
    }
}

// ---------------- fallback: single-WG kernel ----------------
__global__ __launch_bounds__(1024, 1)
void jansen_main(const float* __restrict__ inp, const float* __restrict__ noise_in,
                 const float* __restrict__ hx,  const float* __restrict__ hE,
                 const float* __restrict__ sc,  const float* __restrict__ wbb,
                 const float* __restrict__ lm,  const int*   __restrict__ delays,
                 float* __restrict__ out, float* __restrict__ ws)
{
    const int tid = threadIdx.x;
    const int i   = tid & 255;
    const int c   = tid >> 8;

    float* ring = ws;
    float* lmt  = ws + N_NODE * RING;

    __shared__ double red[18];
    __shared__ float  part[4][N_NODE];
    __shared__ float  wn[N_NODE * N_NODE];

    double ssq = 0.0;
    for (int p = tid; p < N_NODE * N_NODE; p += 1024) {
        int r0 = p / N_NODE;
        int cc = p - r0 * N_NODE;
        float w1 = expf(wbb[p]) * sc[p];
        float w2 = expf(wbb[cc * N_NODE + r0]) * sc[cc * N_NODE + r0];
        float v  = log1pf(0.5f * (w1 + w2));
        wn[p] = v;
        ssq += (double)v * (double)v;
    }
    #pragma unroll
    for (int off = 32; off > 0; off >>= 1) ssq += __shfl_down(ssq, off, 64);
    if ((tid & 63) == 0) red[tid >> 6] = ssq;
    __syncthreads();
    if (tid == 0) {
        double s = 0.0;
        for (int k = 0; k < 16; ++k) s += red[k];
        red[16] = 1.0 / sqrt(s);
    }
    __syncthreads();
    const float inv_norm = (float)red[16];
    for (int p = tid; p < N_NODE * N_NODE; p += 1024) wn[p] *= inv_norm;

    for (int p = tid; p < N_NODE * 500; p += 1024) {
        int j = p / 500, dd = p - j * 500;
        ring[j * RING + (511 - dd)] = hE[p];
    }
    if (tid < 64) {
        float s = 0.0f;
        for (int n = 0; n < N_NODE; ++n) { float v = lm[tid * N_NODE + n]; s += v * v; }
        float inv = 1.0f / sqrtf(s);
        for (int n = 0; n < N_NODE; ++n) lmt[tid * N_NODE + n] = lm[tid * N_NODE + n] * inv;
    }
    __syncthreads();
    if (tid < N_NODE) {
        float s = 0.0f;
        for (int o = 0; o < 64; ++o) s += lmt[o * N_NODE + tid];
        s *= (1.0f / 64.0f);
        for (int o = 0; o < 64; ++o) lmt[o * N_NODE + tid] -= s;
    }

    unsigned int dpk[25];
    if (i < N_NODE) {
        #pragma unroll
        for (int r0 = 0; r0 < 25; ++r0) {
            int d0 = delays[(c * 50 + 2 * r0    ) * N_NODE + i];
            int d1 = delays[(c * 50 + 2 * r0 + 1) * N_NODE + i];
            unsigned e0 = (unsigned)((-1 - d0) & 511);
            unsigned e1 = (unsigned)((-1 - d1) & 511);
            dpk[r0] = e0 | (e1 << 16);
        }
    }

    float M = 0, E = 0, I = 0, Mvv = 0, Evv = 0, Ivv = 0, rowsum = 0;
    if (c == 0 && i < N_NODE) {
        M   = hx[i * 6 + 0]; E   = hx[i * 6 + 1]; I   = hx[i * 6 + 2];
        Mvv = hx[i * 6 + 3]; Evv = hx[i * 6 + 4]; Ivv = hx[i * 6 + 5];
    }
    __syncthreads();
    if (c == 0 && i < N_NODE) {
        float s = 0.0f;
        for (int j = 0; j < N_NODE; ++j) s += wn[j * N_NODE + i];
        rowsum = s;
    }

    for (int t = 0; t < NSTEP; ++t) {
        if (i < N_NODE) {
            float acc = 0.0f;
            const float* ringc = ring + c * 50 * RING;
            const float* wnc   = wn + c * 50 * N_NODE + i;
            #pragma unroll
            for (int r0 = 0; r0 < 50; ++r0) {
                unsigned e = (dpk[r0 >> 1] >> ((r0 & 1) << 4)) & 0xffffu;
                int pos = (int)(((unsigned)t + e) & 511u);
                acc = fmaf(wnc[r0 * N_NODE], ringc[r0 * RING + pos], acc);
            }
            part[c][i] = acc;
        }
        __syncthreads();
        if (c == 0 && i < N_NODE) {
            float LEd = part[0][i] + part[1][i] + part[2][i] + part[3][i];
            int b = t / 10, h = t - b * 10;
            float u  = inp     [i * 500 + h * 50 + b];
            float nz = noise_in[i * 500 + h * 50 + b];
            float rM = 5.0f / (1.0f + expf(0.56f * (6.0f - (E - I))));
            float rE = 250.0f * nz + 1000.01f * (LEd - rowsum * E) + 108.01f * (5.0f / (1.0f + expf(0.56f * (6.0f - 135.01f * M))));
            float rI = 33.76f * (5.0f / (1.0f + expf(0.56f * (6.0f - 33.76f * M))));
            float ddM = M + 1e-4f * Mvv;
            float ddE = E + 1e-4f * Evv;
            float ddI = I + 1e-4f * Ivv;
            float uu  = u + 500.0f * tanhf(rM / 500.0f);
            float ddMv = Mvv + 1e-4f * (328.25f * uu - 202.0f * Mvv - 10201.0f * M);
            float uE  = 500.0f * tanhf(rE / 500.0f);
            float ddEv = Evv + 1e-4f * (328.25f * uE - 202.0f * Evv - 10201.0f * E);
            float uI  = 500.0f * tanhf(rI / 500.0f);
            float ddIv = Ivv + 1e-4f * (1122.0f * uI - 102.0f * Ivv - 2601.0f * I);
            M   = 1000.0f * tanhf(ddM / 1000.0f);
            E   = 1000.0f * tanhf(ddE / 1000.0f);
            I   = 1000.0f * tanhf(ddI / 1000.0f);
            Mvv = 1000.0f * tanhf(ddMv / 1000.0f);
            Evv = 1000.0f * tanhf(ddEv / 1000.0f);
            Ivv = 1000.0f * tanhf(ddIv / 1000.0f);
            ring[i * RING + (t & 511)] = M;
            if (h == 9) {
                out[ 4400 + i * 50 + b] = E;
                out[14400 + i * 50 + b] = I;
                out[24400 + i * 50 + b] = M;
                out[34400 + i * 50 + b] = Evv;
                out[44400 + i * 50 + b] = Ivv;
                out[54400 + i * 50 + b] = Mvv;
            }
        }
        __syncthreads();
    }

    if (c == 0 && i < N_NODE) {
        out[3200 + i * 6 + 0] = M;
        out[3200 + i * 6 + 1] = E;
        out[3200 + i * 6 + 2] = I;
        out[3200 + i * 6 + 3] = Mvv;
        out[3200 + i * 6 + 4] = Evv;
        out[3200 + i * 6 + 5] = Ivv;
    }
    for (int p = tid; p < N_NODE * 500; p += 1024) {
        int ii = p / 500, dd = p - ii * 500;
        out[64400 + p] = ring[ii * RING + (499 - dd)];
    }
    __syncthreads();
    for (int p = tid; p < 64 * 50; p += 1024) {
        int o = p / 50, b = p - o * 50;
        float s = 0.0f;
        for (int n = 0; n < N_NODE; ++n)
            s += lmt[o * N_NODE + n] * (out[4400 + n * 50 + b] - out[14400 + n * 50 + b]);
        out[p] = 5.0f * s - 2.0f;
    }
}

extern "C" void kernel_launch(void* const* d_in, const int* in_sizes, int n_in,
                              void* d_out, int out_size, void* d_ws, size_t ws_size,
                              hipStream_t stream) {
    if (ws_size >= WS_NEED) {
        zero_bar<<<1, 64, 0, stream>>>((int*)((float*)d_ws + OFF_BAR));
        jansen_tlp<<<NWG, NTHR, 0, stream>>>(
            (const float*)d_in[0], (const float*)d_in[1], (const float*)d_in[2],
            (const float*)d_in[3], (const float*)d_in[4], (const float*)d_in[5],
            (const float*)d_in[6], (const int*)d_in[7],
            (float*)d_out, (float*)d_ws);
    } else {
        jansen_main<<<1, 1024, 0, stream>>>(
            (const float*)d_in[0], (const float*)d_in[1], (const float*)d_in[2],
            (const float*)d_in[3], (const float*)d_in[4], (const float*)d_in[5],
            (const float*)d_in[6], (const int*)d_in[7],
            (float*)d_out, (float*)d_ws);
    }
}

// Round 12
// 1226.680 us; speedup vs baseline: 1.2469x; 1.2469x over previous
//
#include <hip/hip_runtime.h>
#include <math.h>

#define N_NODE 200
#define RING   512
#define ROWF   545          // 512 + 32 mirror + 1 stagger (odd stride -> conflict-free ring writes)
#define NSTEP  500
#define TB     32
#define NB     16           // ceil(500/32); last block kmax=20
#define NWG    8
#define NTHR   256
#define JSL    25           // j-rows per WG slice
#define NEARCAP 32          // near band d < 32
#define MDEP   36           // Mrec depth (>= 33), mod-36 slots
#define MSZ    (MDEP * N_NODE)

// ---- ws layout (float element offsets) ----
#define FPBUF   (NWG * N_NODE * TB)   // 51200 floats per parity buffer
#define OFF_FP  0                     // [2][NWG][200][32] far partials (parity by block&1)
#define OFF_BAR (2 * FPBUF)           // [64] int barrier counters
#define WS_NEED ((size_t)(2 * FPBUF + 64) * 4)

// ---- static LDS layout (byte offsets into smem[]) ----
#define SM_RED   0        // double[8]
#define SM_MREC  64       // float[36*200]            -> 28864
#define SM_US    28864    // float[32][200] u staging  (build phase: nOFF) -> 54464
#define SM_NS    54464    // float[32][200] nz staging (build phase: nW)   -> 80064
#define SM_LED   80864    // float[32*200]            -> 106464
#define SM_RING  106464   // float[25*545] = 54500B   -> 160964
#define SM_TOTAL 160964
// epilogue overlays (post-loop; must stay below SM_RING until hEb flushed)
#define SM_LMT   64       // float[64*200]  -> 51264
#define SM_DIFF  51264    // float[200*50]  -> 91264

// ---- fast transcendentals (v_exp_f32-based, ~1e-6 rel err) ----
__device__ __forceinline__ float ftanh(float x) {
    float ax = fabsf(x);
    float t  = __expf(-2.0f * ax);
    float r  = __fdividef(1.0f - t, 1.0f + t);
    return copysignf(r, x);
}
__device__ __forceinline__ float sigm(float x) {
    return __fdividef(5.0f, 1.0f + __expf(0.56f * (6.0f - x)));
}
__device__ __forceinline__ float satf(float x) {
    return 1000.0f * ftanh(x * 0.001f);
}

__device__ __forceinline__ void grid_barrier(int* slot, int nwg) {
    __syncthreads();
    if (threadIdx.x == 0) {
        __threadfence();
        __hip_atomic_fetch_add(slot, 1, __ATOMIC_ACQ_REL, __HIP_MEMORY_SCOPE_AGENT);
        while (__hip_atomic_load(slot, __ATOMIC_ACQUIRE, __HIP_MEMORY_SCOPE_AGENT) < nwg) {
            __builtin_amdgcn_s_sleep(2);
        }
        __threadfence();
    }
    __syncthreads();
}

__global__ void zero_bar(int* bar) {
    if (threadIdx.x < 64) bar[threadIdx.x] = 0;
}

__global__ __launch_bounds__(NTHR, 1)
void jansen_pf(const float* __restrict__ inp, const float* __restrict__ noise_in,
               const float* __restrict__ hx,  const float* __restrict__ hE,
               const float* __restrict__ sc,  const float* __restrict__ wbb,
               const float* __restrict__ lm,  const int*   __restrict__ delays,
               float* __restrict__ out, float* __restrict__ ws)
{
    __shared__ char smem[SM_TOTAL];
    double*   red  = (double*)(smem + SM_RED);
    float*    Mrec = (float*)(smem + SM_MREC);
    unsigned* nOFF = (unsigned*)(smem + SM_US);   // build-phase alias
    float*    nW   = (float*)(smem + SM_NS);      // build-phase alias
    float*    uS   = (float*)(smem + SM_US);      // main-loop alias
    float*    nS   = (float*)(smem + SM_NS);      // main-loop alias
    float*    LEdS = (float*)(smem + SM_LED);
    float*    ringS= (float*)(smem + SM_RING);

    const int tid = threadIdx.x;
    const int wg  = blockIdx.x;
    const int i   = tid;            // node id (active if < 200)
    const int jlo = wg * JSL;

    float* fp  = ws + OFF_FP;
    int*   bar = (int*)(ws + OFF_BAR);

    // ---- pass A: Frobenius norm of wl (redundant per WG; exact libm) ----
    double ssq = 0.0;
    for (int q = tid; q < N_NODE * N_NODE; q += NTHR) {
        int j = q / N_NODE, ii = q - j * N_NODE;
        float w1 = expf(wbb[ii * N_NODE + j]) * sc[ii * N_NODE + j];
        float w2 = expf(wbb[j * N_NODE + ii]) * sc[j * N_NODE + ii];
        float wl = log1pf(0.5f * (w1 + w2));
        ssq += (double)wl * (double)wl;
    }
    #pragma unroll
    for (int off = 32; off > 0; off >>= 1) ssq += __shfl_down(ssq, off, 64);
    if ((tid & 63) == 0) red[tid >> 6] = ssq;

    // ---- ring init: pos x holds M[-1-dd], dd=511-x; mirror [512..543] copies [0..31] ----
    for (int p = tid; p < JSL * ROWF; p += NTHR) {
        int jl = p / ROWF, x = p - jl * ROWF;
        float v = 0.0f;
        if (x < 544) {
            int dd = (x < RING) ? (511 - x) : (1023 - x);
            if (dd < 500) v = hE[(jlo + jl) * 500 + dd];
        }
        ringS[p] = v;
    }
    // ---- Mrec init: M[-q] at slot (36-q), q=1..32 -> slot s in [4,35]: hE[j][35-s] ----
    for (int p = tid; p < MSZ; p += NTHR) {
        int s = p / N_NODE, j = p - s * N_NODE;
        Mrec[p] = (s >= 4) ? hE[j * 500 + (35 - s)] : 0.0f;
    }
    // ---- zero-init near tables (padding entries: offset 0, weight 0) ----
    for (int p = tid; p < NEARCAP * N_NODE; p += NTHR) {
        nOFF[p] = 0u;
        nW[p]   = 0.0f;
    }
    __syncthreads();
    if (tid == 0) {
        double s = 0.0;
        #pragma unroll
        for (int r = 0; r < 4; ++r) s += red[r];
        red[0] = 1.0 / sqrt(s);
    }
    __syncthreads();
    const float inv = (float)red[0];

    // ---- pass B: near lists (transposed build), own-slice far weights, state ----
    float rowsum = 0.0f;
    float M = 0, E = 0, I = 0, Mvv = 0, Evv = 0, Ivv = 0;
    float wreg[JSL];
    int   ereg[JSL];
    #pragma unroll
    for (int jl = 0; jl < JSL; ++jl) { wreg[jl] = 0.0f; ereg[jl] = 0; }
    if (i < N_NODE) {
        int cnt = 0;
        for (int j = 0; j < N_NODE; ++j) {
            float w1 = expf(wbb[i * N_NODE + j]) * sc[i * N_NODE + j];
            float w2 = expf(wbb[j * N_NODE + i]) * sc[j * N_NODE + i];
            float w  = log1pf(0.5f * (w1 + w2)) * inv;
            int d = delays[j * N_NODE + i];
            rowsum += w;
            if (d < NEARCAP && cnt < NEARCAP) {
                nOFF[cnt * N_NODE + i] = (unsigned)((35 - d) * N_NODE + j);
                nW  [cnt * N_NODE + i] = w;
                ++cnt;
            }
        }
        #pragma unroll
        for (int jl = 0; jl < JSL; ++jl) {
            int j = jlo + jl;
            float w1 = expf(wbb[i * N_NODE + j]) * sc[i * N_NODE + j];
            float w2 = expf(wbb[j * N_NODE + i]) * sc[j * N_NODE + i];
            float w  = log1pf(0.5f * (w1 + w2)) * inv;
            int d = delays[j * N_NODE + i];
            wreg[jl] = (d < NEARCAP) ? 0.0f : w;
            ereg[jl] = 511 - d;
        }
        M   = hx[i * 6 + 0]; E   = hx[i * 6 + 1]; I   = hx[i * 6 + 2];
        Mvv = hx[i * 6 + 3]; Evv = hx[i * 6 + 4]; Ivv = hx[i * 6 + 5];
    }

    // ---- near list -> REGISTERS (loop-invariant; static indices only) ----
    int   noffR[NEARCAP];
    float nwR[NEARCAP];
    {
        const int ii = (i < N_NODE) ? i : 0;
        #pragma unroll
        for (int n = 0; n < NEARCAP; ++n) {
            noffR[n] = (int)nOFF[n * N_NODE + ii];
            nwR[n]   = nW[n * N_NODE + ii];
        }
    }
    __syncthreads();   // after this, nOFF/nW memory is reused as uS/nS

    // ---------------- main loop over 32-step blocks (serial phases) ----------------
    for (int b = 0; b < NB; ++b) {
        const int t0 = b * TB;
        float* fpb = fp + (b & 1) * FPBUF;

        // ---- far phase: own j-slice, contiguous mirror-padded reads ----
        if (i < N_NODE) {
            float ac[TB];
            #pragma unroll
            for (int k = 0; k < TB; ++k) ac[k] = 0.0f;
            #pragma unroll
            for (int jl = 0; jl < JSL; ++jl) {
                float w  = wreg[jl];
                int   p0 = (t0 + ereg[jl]) & 511;
                const float* rb = ringS + jl * ROWF + p0;
                #pragma unroll
                for (int k = 0; k < TB; ++k)
                    ac[k] = fmaf(w, rb[k], ac[k]);
            }
            float4* fpw = (float4*)(fpb + wg * (N_NODE * TB) + i * TB);
            #pragma unroll
            for (int q = 0; q < 8; ++q)
                fpw[q] = make_float4(ac[4*q+0], ac[4*q+1], ac[4*q+2], ac[4*q+3]);

            // ---- stage this block's u/noise to LDS (drain absorbed by grid barrier) ----
            #pragma unroll
            for (int k = 0; k < TB; ++k) {
                int t = t0 + k;
                float uv = 0.0f, nv = 0.0f;
                if (t < NSTEP) {
                    int bb = t / 10, h = t - 10 * bb;
                    uv = inp     [i * 500 + h * 50 + bb];
                    nv = noise_in[i * 500 + h * 50 + bb];
                }
                uS[k * N_NODE + i] = uv;
                nS[k * N_NODE + i] = nv;
            }
        }

        grid_barrier(bar + b, NWG);

        // ---- gather partials: 4 rounds of 16 in-flight float4 loads ----
        if (i < N_NODE) {
            const float* basep = fpb + i * TB;
            #pragma unroll
            for (int cp = 0; cp < 4; ++cp) {
                const int c0 = 2 * cp, c1 = 2 * cp + 1;
                float4 qa[8], qb[8];
                #pragma unroll
                for (int g = 0; g < NWG; ++g) {
                    qa[g] = *(const float4*)(basep + g * (N_NODE * TB) + c0 * 4);
                    qb[g] = *(const float4*)(basep + g * (N_NODE * TB) + c1 * 4);
                }
                float sx = 0, sy = 0, sz = 0, sw = 0;
                #pragma unroll
                for (int g = 0; g < NWG; ++g) {
                    sx += qa[g].x; sy += qa[g].y; sz += qa[g].z; sw += qa[g].w;
                }
                LEdS[(c0 * 4 + 0) * N_NODE + i] = sx;
                LEdS[(c0 * 4 + 1) * N_NODE + i] = sy;
                LEdS[(c0 * 4 + 2) * N_NODE + i] = sz;
                LEdS[(c0 * 4 + 3) * N_NODE + i] = sw;
                sx = 0; sy = 0; sz = 0; sw = 0;
                #pragma unroll
                for (int g = 0; g < NWG; ++g) {
                    sx += qb[g].x; sy += qb[g].y; sz += qb[g].z; sw += qb[g].w;
                }
                LEdS[(c1 * 4 + 0) * N_NODE + i] = sx;
                LEdS[(c1 * 4 + 1) * N_NODE + i] = sy;
                LEdS[(c1 * 4 + 2) * N_NODE + i] = sz;
                LEdS[(c1 * 4 + 3) * N_NODE + i] = sw;
            }
        }
        __syncthreads();

        // ---- inner per-step phase (redundant in every WG) ----
        const int kmax = (NSTEP - t0 < TB) ? (NSTEP - t0) : TB;
        int s36 = t0 % MDEP;
        int bcur = t0 / 10, hcur = t0 - 10 * bcur;
        const bool ringw = (i >= jlo) && (i < jlo + JSL);
        const int  rbase = (i - jlo) * ROWF;
        // prime step-0 LEdS/u/n (these LDS regions are read-only during the inner phase,
        // so prefetching across the per-step barrier is safe)
        float ledC = 0.0f, uC = 0.0f, nC = 0.0f;
        if (i < N_NODE) {
            ledC = LEdS[i];
            uC   = uS[i];
            nC   = nS[i];
        }
        for (int k = 0; k < kmax; ++k) {
            const int t = t0 + k;
            if (i < N_NODE) {
                const int base36 = s36 * N_NODE;
                // prefetch next step's LEdS/u/n early (latency hides under ODE chain)
                float ledN = 0.0f, uN = 0.0f, nN = 0.0f;
                if (k + 1 < kmax) {
                    ledN = LEdS[(k + 1) * N_NODE + i];
                    uN   = uS[(k + 1) * N_NODE + i];
                    nN   = nS[(k + 1) * N_NODE + i];
                }
                // fixed-count unrolled near gather, 4 accumulators (independent chains)
                float a0 = ledC;
                float a1 = 0.0f, a2 = 0.0f, a3 = 0.0f;
                #pragma unroll
                for (int n = 0; n < NEARCAP; n += 4) {
                    int d0 = base36 + noffR[n+0]; if (d0 >= MSZ) d0 -= MSZ;
                    int d1 = base36 + noffR[n+1]; if (d1 >= MSZ) d1 -= MSZ;
                    int d2 = base36 + noffR[n+2]; if (d2 >= MSZ) d2 -= MSZ;
                    int d3 = base36 + noffR[n+3]; if (d3 >= MSZ) d3 -= MSZ;
                    a0 = fmaf(nwR[n+0], Mrec[d0], a0);
                    a1 = fmaf(nwR[n+1], Mrec[d1], a1);
                    a2 = fmaf(nwR[n+2], Mrec[d2], a2);
                    a3 = fmaf(nwR[n+3], Mrec[d3], a3);
                }
                float LEd = (a0 + a1) + (a2 + a3);
                float u  = uC;
                float nz = nC;
                float rM = sigm(E - I);
                float rE = 250.0f * nz + 1000.01f * (LEd - rowsum * E) + 108.01f * sigm(135.01f * M);
                float rI = 33.76f * sigm(33.76f * M);
                float ddM = M + 1e-4f * Mvv;
                float ddE = E + 1e-4f * Evv;
                float ddI = I + 1e-4f * Ivv;
                float uu  = u + 500.0f * ftanh(rM * 0.002f);
                float ddMv = Mvv + 1e-4f * (328.25f * uu - 202.0f * Mvv - 10201.0f * M);
                float uE  = 500.0f * ftanh(rE * 0.002f);
                float ddEv = Evv + 1e-4f * (328.25f * uE - 202.0f * Evv - 10201.0f * E);
                float uI  = 500.0f * ftanh(rI * 0.002f);
                float ddIv = Ivv + 1e-4f * (1122.0f * uI - 102.0f * Ivv - 2601.0f * I);
                M   = satf(ddM);  E   = satf(ddE);  I   = satf(ddI);
                Mvv = satf(ddMv); Evv = satf(ddEv); Ivv = satf(ddIv);
                Mrec[base36 + i] = M;
                if (ringw) {
                    int pt = t & 511;
                    ringS[rbase + pt] = M;
                    if (pt < 32) ringS[rbase + pt + 512] = M;
                }
                if (wg == 0 && hcur == 9) {
                    out[ 4400 + i * 50 + bcur] = E;
                    out[14400 + i * 50 + bcur] = I;
                    out[24400 + i * 50 + bcur] = M;
                    out[34400 + i * 50 + bcur] = Evv;
                    out[44400 + i * 50 + bcur] = Ivv;
                    out[54400 + i * 50 + bcur] = Mvv;
                }
                ledC = ledN; uC = uN; nC = nN;
                ++hcur; if (hcur == 10) { hcur = 0; ++bcur; }
                ++s36; if (s36 == MDEP) s36 = 0;
            }
            __syncthreads();
        }
    }

    // ---------------- epilogue ----------------
    // hEb slice: rows [jlo, jlo+JSL) from LDS ring
    for (int p = tid; p < JSL * 500; p += NTHR) {
        int jl = p / 500, dd = p - jl * 500;
        out[64400 + (jlo + jl) * 500 + dd] = ringS[jl * ROWF + ((499 - dd) & 511)];
    }
    if (wg != 0) return;

    if (i < N_NODE) {
        out[3200 + i * 6 + 0] = M;
        out[3200 + i * 6 + 1] = E;
        out[3200 + i * 6 + 2] = I;
        out[3200 + i * 6 + 3] = Mvv;
        out[3200 + i * 6 + 4] = Evv;
        out[3200 + i * 6 + 5] = Ivv;
    }

    float* lmt  = (float*)(smem + SM_LMT);
    float* diff = (float*)(smem + SM_DIFF);
    __syncthreads();
    if (tid < 64) {
        float s = 0.0f;
        for (int n = 0; n < N_NODE; ++n) { float v = lm[tid * N_NODE + n]; s += v * v; }
        float ivn = 1.0f / sqrtf(s);
        for (int n = 0; n < N_NODE; ++n) lmt[tid * N_NODE + n] = lm[tid * N_NODE + n] * ivn;
    }
    __syncthreads();
    if (tid < N_NODE) {
        float s = 0.0f;
        for (int o = 0; o < 64; ++o) s += lmt[o * N_NODE + tid];
        s *= (1.0f / 64.0f);
        for (int o = 0; o < 64; ++o) lmt[o * N_NODE + tid] -= s;
    }
    __syncthreads();
    for (int p = tid; p < 10000; p += NTHR) diff[p] = out[4400 + p] - out[14400 + p];
    __syncthreads();
    for (int p = tid; p < 3200; p += NTHR) {
        int o = p / 50, bb = p - o * 50;
        float s = 0.0f;
        for (int n = 0; n < N_NODE; ++n)
            s = fmaf(lmt[o * N_NODE + n], diff[n * 50 + bb], s);
        out[p] = 5.0f * s - 2.0f;
    }
}

// ---------------- fallback: single-WG kernel ----------------
__global__ __launch_bounds__(1024, 1)
void jansen_main(const float* __restrict__ inp, const float* __restrict__ noise_in,
                 const float* __restrict__ hx,  const float* __restrict__ hE,
                 const float* __restrict__ sc,  const float* __restrict__ wbb,
                 const float* __restrict__ lm,  const int*   __restrict__ delays,
                 float* __restrict__ out, float* __restrict__ ws)
{
    const int tid = threadIdx.x;
    const int i   = tid & 255;
    const int c   = tid >> 8;

    float* ring = ws;
    float* lmt  = ws + N_NODE * RING;

    __shared__ double red[18];
    __shared__ float  part[4][N_NODE];
    __shared__ float  wn[N_NODE * N_NODE];

    double ssq = 0.0;
    for (int p = tid; p < N_NODE * N_NODE; p += 1024) {
        int r0 = p / N_NODE;
        int cc = p - r0 * N_NODE;
        float w1 = expf(wbb[p]) * sc[p];
        float w2 = expf(wbb[cc * N_NODE + r0]) * sc[cc * N_NODE + r0];
        float v  = log1pf(0.5f * (w1 + w2));
        wn[p] = v;
        ssq += (double)v * (double)v;
    }
    #pragma unroll
    for (int off = 32; off > 0; off >>= 1) ssq += __shfl_down(ssq, off, 64);
    if ((tid & 63) == 0) red[tid >> 6] = ssq;
    __syncthreads();
    if (tid == 0) {
        double s = 0.0;
        for (int k = 0; k < 16; ++k) s += red[k];
        red[16] = 1.0 / sqrt(s);
    }
    __syncthreads();
    const float inv_norm = (float)red[16];
    for (int p = tid; p < N_NODE * N_NODE; p += 1024) wn[p] *= inv_norm;

    for (int p = tid; p < N_NODE * 500; p += 1024) {
        int j = p / 500, dd = p - j * 500;
        ring[j * RING + (511 - dd)] = hE[p];
    }
    if (tid < 64) {
        float s = 0.0f;
        for (int n = 0; n < N_NODE; ++n) { float v = lm[tid * N_NODE + n]; s += v * v; }
        float inv = 1.0f / sqrtf(s);
        for (int n = 0; n < N_NODE; ++n) lmt[tid * N_NODE + n] = lm[tid * N_NODE + n] * inv;
    }
    __syncthreads();
    if (tid < N_NODE) {
        float s = 0.0f;
        for (int o = 0; o < 64; ++o) s += lmt[o * N_NODE + tid];
        s *= (1.0f / 64.0f);
        for (int o = 0; o < 64; ++o) lmt[o * N_NODE + tid] -= s;
    }

    unsigned int dpk[25];
    if (i < N_NODE) {
        #pragma unroll
        for (int r0 = 0; r0 < 25; ++r0) {
            int d0 = delays[(c * 50 + 2 * r0    ) * N_NODE + i];
            int d1 = delays[(c * 50 + 2 * r0 + 1) * N_NODE + i];
            unsigned e0 = (unsigned)((-1 - d0) & 511);
            unsigned e1 = (unsigned)((-1 - d1) & 511);
            dpk[r0] = e0 | (e1 << 16);
        }
    }

    float M = 0, E = 0, I = 0, Mvv = 0, Evv = 0, Ivv = 0, rowsum = 0;
    if (c == 0 && i < N_NODE) {
        M   = hx[i * 6 + 0]; E   = hx[i * 6 + 1]; I   = hx[i * 6 + 2];
        Mvv = hx[i * 6 + 3]; Evv = hx[i * 6 + 4]; Ivv = hx[i * 6 + 5];
    }
    __syncthreads();
    if (c == 0 && i < N_NODE) {
        float s = 0.0f;
        for (int j = 0; j < N_NODE; ++j) s += wn[j * N_NODE + i];
        rowsum = s;
    }

    for (int t = 0; t < NSTEP; ++t) {
        if (i < N_NODE) {
            float acc = 0.0f;
            const float* ringc = ring + c * 50 * RING;
            const float* wnc   = wn + c * 50 * N_NODE + i;
            #pragma unroll
            for (int r0 = 0; r0 < 50; ++r0) {
                unsigned e = (dpk[r0 >> 1] >> ((r0 & 1) << 4)) & 0xffffu;
                int pos = (int)(((unsigned)t + e) & 511u);
                acc = fmaf(wnc[r0 * N_NODE], ringc[r0 * RING + pos], acc);
            }
            part[c][i] = acc;
        }
        __syncthreads();
        if (c == 0 && i < N_NODE) {
            float LEd = part[0][i] + part[1][i] + part[2][i] + part[3][i];
            int b = t / 10, h = t - b * 10;
            float u  = inp     [i * 500 + h * 50 + b];
            float nz = noise_in[i * 500 + h * 50 + b];
            float rM = 5.0f / (1.0f + expf(0.56f * (6.0f - (E - I))));
            float rE = 250.0f * nz + 1000.01f * (LEd - rowsum * E) + 108.01f * (5.0f / (1.0f + expf(0.56f * (6.0f - 135.01f * M))));
            float rI = 33.76f * (5.0f / (1.0f + expf(0.56f * (6.0f - 33.76f * M))));
            float ddM = M + 1e-4f * Mvv;
            float ddE = E + 1e-4f * Evv;
            float ddI = I + 1e-4f * Ivv;
            float uu  = u + 500.0f * tanhf(rM / 500.0f);
            float ddMv = Mvv + 1e-4f * (328.25f * uu - 202.0f * Mvv - 10201.0f * M);
            float uE  = 500.0f * tanhf(rE / 500.0f);
            float ddEv = Evv + 1e-4f * (328.25f * uE - 202.0f * Evv - 10201.0f * E);
            float uI  = 500.0f * tanhf(rI / 500.0f);
            float ddIv = Ivv + 1e-4f * (1122.0f * uI - 102.0f * Ivv - 2601.0f * I);
            M   = 1000.0f * tanhf(ddM / 1000.0f);
            E   = 1000.0f * tanhf(ddE / 1000.0f);
            I   = 1000.0f * tanhf(ddI / 1000.0f);
            Mvv = 1000.0f * tanhf(ddMv / 1000.0f);
            Evv = 1000.0f * tanhf(ddEv / 1000.0f);
            Ivv = 1000.0f * tanhf(ddIv / 1000.0f);
            ring[i * RING + (t & 511)] = M;
            if (h == 9) {
                out[ 4400 + i * 50 + b] = E;
                out[14400 + i * 50 + b] = I;
                out[24400 + i * 50 + b] = M;
                out[34400 + i * 50 + b] = Evv;
                out[44400 + i * 50 + b] = Ivv;
                out[54400 + i * 50 + b] = Mvv;
            }
        }
        __syncthreads();
    }

    if (c == 0 && i < N_NODE) {
        out[3200 + i * 6 + 0] = M;
        out[3200 + i * 6 + 1] = E;
        out[3200 + i * 6 + 2] = I;
        out[3200 + i * 6 + 3] = Mvv;
        out[3200 + i * 6 + 4] = Evv;
        out[3200 + i * 6 + 5] = Ivv;
    }
    for (int p = tid; p < N_NODE * 500; p += 1024) {
        int ii = p / 500, dd = p - ii * 500;
        out[64400 + p] = ring[ii * RING + (499 - dd)];
    }
    __syncthreads();
    for (int p = tid; p < 64 * 50; p += 1024) {
        int o = p / 50, b = p - o * 50;
        float s = 0.0f;
        for (int n = 0; n < N_NODE; ++n)
            s += lmt[o * N_NODE + n] * (out[4400 + n * 50 + b] - out[14400 + n * 50 + b]);
        out[p] = 5.0f * s - 2.0f;
    }
}

extern "C" void kernel_launch(void* const* d_in, const int* in_sizes, int n_in,
                              void* d_out, int out_size, void* d_ws, size_t ws_size,
                              hipStream_t stream) {
    if (ws_size >= WS_NEED) {
        zero_bar<<<1, 64, 0, stream>>>((int*)((float*)d_ws + OFF_BAR));
        jansen_pf<<<NWG, NTHR, 0, stream>>>(
            (const float*)d_in[0], (const float*)d_in[1], (const float*)d_in[2],
            (const float*)d_in[3], (const float*)d_in[4], (const float*)d_in[5],
            (const float*)d_in[6], (const int*)d_in[7],
            (float*)d_out, (float*)d_ws);
    } else {
        jansen_main<<<1, 1024, 0, stream>>>(
            (const float*)d_in[0], (const float*)d_in[1], (const float*)d_in[2],
            (const float*)d_in[3], (const float*)d_in[4], (const float*)d_in[5],
            (const float*)d_in[6], (const int*)d_in[7],
            (float*)d_out, (float*)d_ws);
    }
}